// Round 1
// 357.008 us; speedup vs baseline: 1.0410x; 1.0410x over previous
//
#include <hip/hip_runtime.h>

typedef unsigned short u16;
typedef unsigned int   u32;
typedef __attribute__((ext_vector_type(8))) u16  u16x8;
typedef __attribute__((ext_vector_type(4))) float f32x4;

#define N_PTS   131072
#define M_PTS   32768
#define BNCF    0.9999950000374997f

__device__ __forceinline__ float b2f(u16 u) {
    u32 x = ((u32)u) << 16;
    float f;
    __builtin_memcpy(&f, &x, 4);
    return f;
}
__device__ __forceinline__ u16 f2b(float f) {
    u32 x;
    __builtin_memcpy(&x, &f, 4);
    u32 r = x + 0x7fffu + ((x >> 16) & 1u);
    return (u16)(r >> 16);
}
__device__ __forceinline__ float silu_f(float x) {
    return x / (1.0f + __expf(-x));
}

__device__ __forceinline__ f32x4 mfma_bf16(u16x8 a, u16x8 b, f32x4 c) {
    asm volatile("v_mfma_f32_16x16x32_bf16 %0, %1, %2, %0"
                 : "+v"(c) : "v"(a), "v"(b));
    return c;
}
// MAI->VALU wait-state guard.
__device__ __forceinline__ f32x4 acc_fence(f32x4 c) {
    asm volatile("s_nop 7\n\ts_nop 7\n\ts_nop 3" : "+v"(c));
    return c;
}

// async global->LDS, 16B per lane. LDS dest = wave-uniform base + lane*16.
__device__ __forceinline__ void cp_glds16(const u16* g, u16* l) {
    typedef const __attribute__((address_space(1))) u32* gp1_t;
    typedef __attribute__((address_space(3))) u32* lp3_t;
    __builtin_amdgcn_global_load_lds((gp1_t)(unsigned long long)g,
                                     (lp3_t)(unsigned long long)l, 16, 0, 0);
}

// ---------------------------------------------------------------- all weight transposes in ONE dispatch
__global__ __launch_bounds__(256) void k_prep(const float* __restrict__ expw, u16* __restrict__ expwt,
                                              const float* __restrict__ pw1w, u16* __restrict__ pw1t,
                                              const float* __restrict__ pw2w, u16* __restrict__ pw2t,
                                              const float* __restrict__ prjw, u16* __restrict__ prjt,
                                              const float* __restrict__ lw1,  u16* __restrict__ lw1t,
                                              const float* __restrict__ lw2,  u16* __restrict__ lw2t,
                                              const float* __restrict__ sw1,  u16* __restrict__ sw1t,
                                              const float* __restrict__ sw2,  u16* __restrict__ sw2t) {
    int idx = blockIdx.x * 256 + threadIdx.x;
    const float* W; u16* O; int K, Kp, Nn;
    if (idx < 65536)                 { W = expw; O = expwt; K = 128; Kp = 128; Nn = 512; }
    else if ((idx -= 65536) < 262144){ W = pw1w; O = pw1t;  K = 512; Kp = 512; Nn = 512; }
    else if ((idx -= 262144) < 262144){ W = pw2w; O = pw2t; K = 512; Kp = 512; Nn = 512; }
    else if ((idx -= 262144) < 65536){ W = prjw; O = prjt;  K = 512; Kp = 512; Nn = 128; }
    else if ((idx -= 65536) < 4096)  { W = lw1;  O = lw1t;  K = 39;  Kp = 64;  Nn = 64;  }
    else if ((idx -= 4096) < 8192)   { W = lw2;  O = lw2t;  K = 64;  Kp = 64;  Nn = 128; }
    else if ((idx -= 8192) < 8192)   { W = sw1;  O = sw1t;  K = 97;  Kp = 128; Nn = 64;  }
    else if ((idx -= 8192) < 2048)   { W = sw2;  O = sw2t;  K = 64;  Kp = 64;  Nn = 32;  }
    else return;
    int n = idx / Kp, k = idx % Kp;
    O[idx] = (k < K) ? f2b(W[(long)k * Nn + n]) : (u16)0;
}

// ---------------------------------------------------------------- centers
__global__ __launch_bounds__(256) void k_centers(const float* __restrict__ pos,
                                                 const float* __restrict__ sfv,
                                                 const int* __restrict__ batch,
                                                 float* __restrict__ acc) {
    __shared__ float ls[16];
    int t = threadIdx.x;
    if (t < 16) ls[t] = 0.0f;
    __syncthreads();
    int i = blockIdx.x * 256 + t;
    if (i < N_PTS) {
        int b = batch[i];
        float inv = 1.0f / sfv[b];
        atomicAdd(&ls[b * 4 + 0], pos[i * 3 + 0] * inv);
        atomicAdd(&ls[b * 4 + 1], pos[i * 3 + 1] * inv);
        atomicAdd(&ls[b * 4 + 2], pos[i * 3 + 2] * inv);
        atomicAdd(&ls[b * 4 + 3], 1.0f);
    }
    __syncthreads();
    if (t < 16) atomicAdd(&acc[t], ls[t]);
}

// ---------------------------------------------------------------- stem (MFMA)
// Feature phase split across lane pairs: each of 2 lanes computes 24 sincos for
// one point, stats merged via shfl_xor(1); normalized bf16 written directly
// (packed b128) — kills the serial 97-iter renormalize loop and half-block idling.
__global__ __launch_bounds__(256) void k_stem(const float* __restrict__ pos,
                                              const float* __restrict__ refl,
                                              const float* __restrict__ sfv,
                                              const int* __restrict__ batch,
                                              const float* __restrict__ cacc,
                                              const float* __restrict__ g,
                                              const float* __restrict__ bb,
                                              const u16* __restrict__ w1t,   // [64][128] bf16 (zero pad k>=97)
                                              const float* __restrict__ b1,
                                              const u16* __restrict__ w2t,   // [32][64] bf16
                                              const float* __restrict__ b2,
                                              u16* __restrict__ xout) {
    __shared__ u16 xs[128][136];
    __shared__ u16 hb[128][72];
    __shared__ u16 w1s[64][136];
    __shared__ u16 w2s[32][72];
    __shared__ float b1s[64];
    __shared__ float b2s[32];
    const float FLO[8] = {
        1.0f, 0.31622776601683794f, 0.1f, 0.031622776601683791f,
        0.01f, 0.0031622776601683794f, 0.001f, 0.00031622776601683794f};
    const float FHI[8] = {
        0.0001f, 3.1622776601683795e-05f, 1e-05f, 3.1622776601683796e-06f,
        1e-06f, 3.1622776601683797e-07f, 1e-07f, 3.1622776601683792e-08f};
    int t = threadIdx.x;
    int wave = t >> 6, lane = t & 63;
    int quad = lane >> 4, l16 = lane & 15;
    int mt0 = wave * 2;

    // zero ALL of xs: 128*136 u16 = 2176 uint4
    for (int u = t; u < 2176; u += 256) ((uint4*)xs)[u] = (uint4){0, 0, 0, 0};
    for (int u = t; u < 1024; u += 256) {
        int row = u >> 4, c8 = (u & 15) * 8;
        *(uint4*)(&w1s[row][c8]) = *(const uint4*)(w1t + row * 128 + c8);
    }
    {
        int row = t >> 3, c8 = (t & 7) * 8;
        *(uint4*)(&w2s[row][c8]) = *(const uint4*)(w2t + row * 64 + c8);
    }
    if (t < 64) b1s[t] = b1[t];
    if (t < 32) b2s[t] = b2[t];
    __syncthreads();

    {
        int p = t >> 1, half = t & 1;
        int i = blockIdx.x * 128 + p;
        int b = batch[i];
        float s = 1.0f / sfv[b];
        float cnt = fmaxf(cacc[b * 4 + 3], 1.0f);
        float npv[3];
#pragma unroll
        for (int d = 0; d < 3; ++d)
            npv[d] = pos[i * 3 + d] * s - cacc[b * 4 + d] / cnt;

        float fq[8];
#pragma unroll
        for (int f = 0; f < 8; ++f) fq[f] = half ? FHI[f] : FLO[f];

        float sv[3][8], cv[3][8];
        float sum = 0.0f, sq = 0.0f;
#pragma unroll
        for (int d = 0; d < 3; ++d) {
#pragma unroll
            for (int f = 0; f < 8; ++f) {
                float a = npv[d] * fq[f];
                float s_, c_;
                __sincosf(a, &s_, &c_);
                sv[d][f] = s_;
                cv[d][f] = c_;
                sum += s_ + c_;
                sq += s_ * s_ + c_ * c_;
            }
        }
        float rf = refl[i];
        if (half == 0) { sum += rf; sq += rf * rf; }
        sum += __shfl_xor(sum, 1);
        sq  += __shfl_xor(sq, 1);

        float m = sum * (1.0f / 97.0f);
        float var = sq * (1.0f / 97.0f) - m * m;
        float rstd = rsqrtf(fmaxf(var, 0.0f) + 1e-5f);

#pragma unroll
        for (int d = 0; d < 3; ++d) {
            int c0 = d * 32 + half * 8;          // sin block
            {
                f32x4 g0  = *(const f32x4*)(g + c0);
                f32x4 g1  = *(const f32x4*)(g + c0 + 4);
                f32x4 bb0 = *(const f32x4*)(bb + c0);
                f32x4 bb1 = *(const f32x4*)(bb + c0 + 4);
                u16 tmp[8];
#pragma unroll
                for (int f = 0; f < 4; ++f) {
                    float v0 = b2f(f2b(sv[d][f]));        // match old bf16 round-trip
                    tmp[f] = f2b((v0 - m) * rstd * g0[f] + bb0[f]);
                    float v1 = b2f(f2b(sv[d][4 + f]));
                    tmp[4 + f] = f2b((v1 - m) * rstd * g1[f] + bb1[f]);
                }
                *(uint4*)(&xs[p][c0]) = *(uint4*)tmp;
            }
            int c1 = d * 32 + 16 + half * 8;     // cos block
            {
                f32x4 g0  = *(const f32x4*)(g + c1);
                f32x4 g1  = *(const f32x4*)(g + c1 + 4);
                f32x4 bb0 = *(const f32x4*)(bb + c1);
                f32x4 bb1 = *(const f32x4*)(bb + c1 + 4);
                u16 tmp[8];
#pragma unroll
                for (int f = 0; f < 4; ++f) {
                    float v0 = b2f(f2b(cv[d][f]));
                    tmp[f] = f2b((v0 - m) * rstd * g0[f] + bb0[f]);
                    float v1 = b2f(f2b(cv[d][4 + f]));
                    tmp[4 + f] = f2b((v1 - m) * rstd * g1[f] + bb1[f]);
                }
                *(uint4*)(&xs[p][c1]) = *(uint4*)tmp;
            }
        }
        if (half == 0) {
            float v = b2f(f2b(rf));
            xs[p][96] = f2b((v - m) * rstd * g[96] + bb[96]);
        }
    }
    __syncthreads();

    {
        f32x4 acc[2][4];
#pragma unroll
        for (int i = 0; i < 2; ++i)
#pragma unroll
            for (int j = 0; j < 4; ++j) acc[i][j] = (f32x4){0.f, 0.f, 0.f, 0.f};
#pragma unroll
        for (int kk = 0; kk < 128; kk += 32) {
            u16x8 af[2], bfr[4];
#pragma unroll
            for (int i = 0; i < 2; ++i)
                af[i] = *(const u16x8*)(&xs[(mt0 + i) * 16 + l16][kk + quad * 8]);
#pragma unroll
            for (int j = 0; j < 4; ++j)
                bfr[j] = *(const u16x8*)(&w1s[j * 16 + l16][kk + quad * 8]);
#pragma unroll
            for (int i = 0; i < 2; ++i)
#pragma unroll
                for (int j = 0; j < 4; ++j)
                    acc[i][j] = mfma_bf16(af[i], bfr[j], acc[i][j]);
        }
#pragma unroll
        for (int i = 0; i < 2; ++i)
#pragma unroll
            for (int j = 0; j < 4; ++j) {
                f32x4 c = acc_fence(acc[i][j]);
                int n = j * 16 + l16;
#pragma unroll
                for (int r = 0; r < 4; ++r)
                    hb[(mt0 + i) * 16 + quad * 4 + r][n] =
                        f2b(silu_f(BNCF * (c[r] + b1s[n])));
            }
    }
    __syncthreads();

    {
        f32x4 acc[2][2];
#pragma unroll
        for (int i = 0; i < 2; ++i)
#pragma unroll
            for (int j = 0; j < 2; ++j) acc[i][j] = (f32x4){0.f, 0.f, 0.f, 0.f};
#pragma unroll
        for (int kk = 0; kk < 64; kk += 32) {
            u16x8 af[2], bfr[2];
#pragma unroll
            for (int i = 0; i < 2; ++i)
                af[i] = *(const u16x8*)(&hb[(mt0 + i) * 16 + l16][kk + quad * 8]);
#pragma unroll
            for (int j = 0; j < 2; ++j)
                bfr[j] = *(const u16x8*)(&w2s[j * 16 + l16][kk + quad * 8]);
#pragma unroll
            for (int i = 0; i < 2; ++i)
#pragma unroll
                for (int j = 0; j < 2; ++j)
                    acc[i][j] = mfma_bf16(af[i], bfr[j], acc[i][j]);
        }
#pragma unroll
        for (int i = 0; i < 2; ++i)
#pragma unroll
            for (int j = 0; j < 2; ++j) {
                f32x4 c = acc_fence(acc[i][j]);
                int n = j * 16 + l16;
#pragma unroll
                for (int r = 0; r < 4; ++r) {
                    int m = (mt0 + i) * 16 + quad * 4 + r;
                    long ig = (long)blockIdx.x * 128 + m;
                    xout[ig * 32 + n] = f2b(silu_f(BNCF * (c[r] + b2s[n])));
                }
            }
    }
}

// ---------------------------------------------------------------- sfeat
__global__ __launch_bounds__(256) void k_sfeat(const float* __restrict__ pos,
                                               const int* __restrict__ idxp,
                                               const int* __restrict__ colp,
                                               const float* __restrict__ lkw,
                                               const float* __restrict__ lkb,
                                               const float* __restrict__ lng,
                                               const float* __restrict__ lnb,
                                               float* __restrict__ sfeat) {
    int r = blockIdx.x * 256 + threadIdx.x;
    if (r >= M_PTS) return;
    int ci = idxp[r];
    float cx = pos[ci * 3 + 0];
    float cy = pos[ci * 3 + 1];
    float cz = pos[ci * 3 + 2];
    float dsx = 0.0f, dsy = 0.0f, dsz = 0.0f;
    for (int e = 0; e < 16; ++e) {
        int c = colp[r * 16 + e];
        float dx = pos[c * 3 + 0] - cx;
        float dy = pos[c * 3 + 1] - cy;
        float dz = pos[c * 3 + 2] - cz;
        float nrm = sqrtf(dx * dx + dy * dy + dz * dz);
        float inv = 1.0f / (nrm + 1e-8f);
        dsx += dx * inv;
        dsy += dy * inv;
        dsz += dz * inv;
    }
    const float S3 = 0.57735026918962576f;
    const float sx[8] = {1, -1, 1, 1, -1, -1, 1, -1};
    const float sy[8] = {1, 1, -1, 1, -1, 1, -1, -1};
    const float sz[8] = {1, 1, 1, -1, 1, -1, -1, -1};
    float sc[3] = {lkb[0], lkb[1], lkb[2]};
#pragma unroll
    for (int j = 0; j < 8; ++j) {
        float nb = (sx[j] * dsx + sy[j] * dsy + sz[j] * dsz) * (S3 * (1.0f / 16.0f));
        sc[0] += nb * lkw[j * 3 + 0];
        sc[1] += nb * lkw[j * 3 + 1];
        sc[2] += nb * lkw[j * 3 + 2];
    }
    float m = (sc[0] + sc[1] + sc[2]) * (1.0f / 3.0f);
    float v = ((sc[0] - m) * (sc[0] - m) + (sc[1] - m) * (sc[1] - m) +
               (sc[2] - m) * (sc[2] - m)) * (1.0f / 3.0f);
    float rstd = rsqrtf(fmaxf(v, 0.0f) + 1e-5f);
#pragma unroll
    for (int c = 0; c < 3; ++c)
        sfeat[r * 3 + c] = (sc[c] - m) * rstd * lng[c] + lnb[c];
}

// ---------------------------------------------------------------- edge MLP + segment max (MFMA)
// LDS cut 47.1KB -> 37.6KB (4 blocks/CU): h overwrites msg in-place (each wave
// reads/writes only its own 32 rows of uni16), w1/w2 time-share one ws buffer.
__global__ __launch_bounds__(256) void k_edge(const float* __restrict__ pos,
                                              const float* __restrict__ refl,
                                              const int* __restrict__ idxp,
                                              const int* __restrict__ colp,
                                              const u16* __restrict__ xfeat,
                                              const float* __restrict__ sfeat,
                                              const u16* __restrict__ w1t,
                                              const float* __restrict__ b1,
                                              const u16* __restrict__ w2t,
                                              const float* __restrict__ b2,
                                              float* __restrict__ agg,
                                              u16* __restrict__ aggb) {
    __shared__ u16 uni16[128 * 72];   // msg bf16 -> h bf16 (per-wave row reuse)
    __shared__ u16 ws[128 * 72];      // w1 (rows 0..63) -> w2 (rows 0..127)
    __shared__ float b1s[64];
    __shared__ float b2s[128];
    int t = threadIdx.x;
    int r0 = blockIdx.x * 8;
    long e0 = (long)r0 * 16;
    int wave = t >> 6, lane = t & 63;
    int quad = lane >> 4, l16 = lane & 15;
    int mt0 = wave * 2;

    for (int u = t; u < 512; u += 256) {
        int row = u >> 3, c8 = (u & 7) * 8;
        *(uint4*)(&ws[row * 72 + c8]) = *(const uint4*)(w1t + row * 64 + c8);
    }
    if (t < 64) b1s[t] = b1[t] * BNCF;     // pre-scale: BNCF*(c+b) = fma(BNCF,c,BNCF*b)
    if (t < 128) b2s[t] = b2[t] * BNCF;

    for (int u = t; u < 512; u += 256) {
        int e = u >> 2, seg = u & 3;
        int c = colp[e0 + e];
        uint4 d = *(const uint4*)(xfeat + (long)c * 32 + seg * 8);
        *(uint4*)(&uni16[e * 72 + seg * 8]) = d;
    }
    if (t < 128) {
        int e = t;
        int r = r0 + (e >> 4);
        int c = colp[e0 + e];
        int ci = idxp[r];
        u16 tmp[8];
        tmp[0] = f2b(pos[c * 3 + 0] - pos[ci * 3 + 0]);
        tmp[1] = f2b(pos[c * 3 + 1] - pos[ci * 3 + 1]);
        tmp[2] = f2b(pos[c * 3 + 2] - pos[ci * 3 + 2]);
        tmp[3] = f2b(refl[c] - refl[ci]);
        tmp[4] = f2b(sfeat[r * 3 + 0]);
        tmp[5] = f2b(sfeat[r * 3 + 1]);
        tmp[6] = f2b(sfeat[r * 3 + 2]);
        tmp[7] = 0;
        *(uint4*)(&uni16[e * 72 + 32]) = *(uint4*)tmp;
        uint4 z = {0, 0, 0, 0};
        *(uint4*)(&uni16[e * 72 + 40]) = z;
        *(uint4*)(&uni16[e * 72 + 48]) = z;
        *(uint4*)(&uni16[e * 72 + 56]) = z;
    }
    __syncthreads();

    {
        f32x4 acc[2][4];
#pragma unroll
        for (int i = 0; i < 2; ++i)
#pragma unroll
            for (int j = 0; j < 4; ++j) acc[i][j] = (f32x4){0.f, 0.f, 0.f, 0.f};
#pragma unroll
        for (int kk = 0; kk < 64; kk += 32) {
            u16x8 af[2], bfr[4];
#pragma unroll
            for (int i = 0; i < 2; ++i)
                af[i] = *(const u16x8*)(&uni16[((mt0 + i) * 16 + l16) * 72 + kk + quad * 8]);
#pragma unroll
            for (int j = 0; j < 4; ++j)
                bfr[j] = *(const u16x8*)(&ws[(j * 16 + l16) * 72 + kk + quad * 8]);
#pragma unroll
            for (int i = 0; i < 2; ++i)
#pragma unroll
                for (int j = 0; j < 4; ++j)
                    acc[i][j] = mfma_bf16(af[i], bfr[j], acc[i][j]);
        }
        // h overwrites the msg rows this same wave just consumed (rows wave*32..+31).
#pragma unroll
        for (int i = 0; i < 2; ++i)
#pragma unroll
            for (int j = 0; j < 4; ++j) {
                f32x4 c = acc_fence(acc[i][j]);
                int n = j * 16 + l16;
#pragma unroll
                for (int r = 0; r < 4; ++r) {
                    float v = silu_f(fmaf(BNCF, c[r], b1s[n]));
                    uni16[((mt0 + i) * 16 + quad * 4 + r) * 72 + n] = f2b(v);
                }
            }
    }
    __syncthreads();      // all w1 reads done, all h visible

    for (int u = t; u < 1024; u += 256) {
        int row = u >> 3, c8 = (u & 7) * 8;
        *(uint4*)(&ws[row * 72 + c8]) = *(const uint4*)(w2t + row * 64 + c8);
    }
    __syncthreads();

    {
        f32x4 acc[2][8];
#pragma unroll
        for (int i = 0; i < 2; ++i)
#pragma unroll
            for (int j = 0; j < 8; ++j) acc[i][j] = (f32x4){0.f, 0.f, 0.f, 0.f};
#pragma unroll
        for (int kk = 0; kk < 64; kk += 32) {
            u16x8 af[2], bfr[8];
#pragma unroll
            for (int i = 0; i < 2; ++i)
                af[i] = *(const u16x8*)(&uni16[((mt0 + i) * 16 + l16) * 72 + kk + quad * 8]);
#pragma unroll
            for (int j = 0; j < 8; ++j)
                bfr[j] = *(const u16x8*)(&ws[(j * 16 + l16) * 72 + kk + quad * 8]);
#pragma unroll
            for (int i = 0; i < 2; ++i)
#pragma unroll
                for (int j = 0; j < 8; ++j)
                    acc[i][j] = mfma_bf16(af[i], bfr[j], acc[i][j]);
        }
        // max_e silu(x_e) == max(silu(max x), silu(min x)) — silu quasiconvex.
#pragma unroll
        for (int i = 0; i < 2; ++i) {
            int rg = r0 + mt0 + i;
#pragma unroll
            for (int j = 0; j < 8; ++j) {
                f32x4 c = acc_fence(acc[i][j]);
                int n = j * 16 + l16;
                float mx = fmaxf(fmaxf(c[0], c[1]), fmaxf(c[2], c[3]));
                float mn = fminf(fminf(c[0], c[1]), fminf(c[2], c[3]));
                mx = fmaxf(mx, __shfl_xor(mx, 16));
                mx = fmaxf(mx, __shfl_xor(mx, 32));
                mn = fminf(mn, __shfl_xor(mn, 16));
                mn = fminf(mn, __shfl_xor(mn, 32));
                if (quad == 0) {
                    float v = fmaxf(silu_f(fmaf(BNCF, mx, b2s[n])),
                                    silu_f(fmaf(BNCF, mn, b2s[n])));
                    agg[(long)rg * 128 + n] = v;
                    aggb[(long)rg * 128 + n] = f2b(v);
                }
            }
        }
    }
}

// ---------------------------------------------------------------- MFMA GEMM (async staging + XOR swizzle)
// LDS tiles unpadded [128][64] u16. LDS (row, chunk c) holds global chunk c^(row&7).
template <int EPI, int OD>
__global__ __launch_bounds__(256) void k_mgemm(const u16* __restrict__ A,
                                               const u16* __restrict__ Bt,
                                               const float* __restrict__ bias,
                                               const float* __restrict__ dww,
                                               const float* __restrict__ dwb,
                                               const float* __restrict__ res,
                                               void* __restrict__ Ov,
                                               int K, int Nn) {
    __shared__ u16 As[128 * 64];
    __shared__ u16 Bs[128 * 64];
    int t = threadIdx.x;
    int wave = t >> 6, lane = t & 63;
    int quad = lane >> 4, l16 = lane & 15;
    int R0 = blockIdx.y * 128, C0 = blockIdx.x * 128;
    int wm = (wave & 1) * 64, wn = (wave >> 1) * 64;

    int srow = (lane >> 3);                 // 0..7 within 8-row group
    int sch  = lane & 7;                    // 16B chunk 0..7

    f32x4 acc[4][4];
#pragma unroll
    for (int i = 0; i < 4; ++i)
#pragma unroll
        for (int j = 0; j < 4; ++j) acc[i][j] = (f32x4){0.f, 0.f, 0.f, 0.f};

    for (int k0 = 0; k0 < K; k0 += 64) {
#pragma unroll
        for (int it = 0; it < 4; ++it) {
            int base = wave * 32 + it * 8;
            int row = base + srow;
            int gch = (sch ^ (row & 7)) << 3;   // swizzled source chunk
            cp_glds16(A  + (long)(R0 + row) * K + k0 + gch, &As[base * 64]);
            cp_glds16(Bt + (long)(C0 + row) * K + k0 + gch, &Bs[base * 64]);
        }
        __syncthreads();
#pragma unroll
        for (int kk = 0; kk < 64; kk += 32) {
            int kb = kk >> 3;                    // 0 or 4
            u16x8 af[4], bfr[4];
#pragma unroll
            for (int tm = 0; tm < 4; ++tm) {
                int r = wm + tm * 16 + l16;
                af[tm] = *(const u16x8*)(&As[r * 64 + (((kb + quad) ^ (r & 7)) << 3)]);
            }
#pragma unroll
            for (int tn = 0; tn < 4; ++tn) {
                int r = wn + tn * 16 + l16;
                bfr[tn] = *(const u16x8*)(&Bs[r * 64 + (((kb + quad) ^ (r & 7)) << 3)]);
            }
#pragma unroll
            for (int tm = 0; tm < 4; ++tm)
#pragma unroll
                for (int tn = 0; tn < 4; ++tn)
                    acc[tm][tn] = mfma_bf16(af[tm], bfr[tn], acc[tm][tn]);
        }
        __syncthreads();
    }

#pragma unroll
    for (int tm = 0; tm < 4; ++tm) {
#pragma unroll
        for (int tn = 0; tn < 4; ++tn) {
            f32x4 c = acc_fence(acc[tm][tn]);
            int n = C0 + wn + tn * 16 + l16;
#pragma unroll
            for (int r = 0; r < 4; ++r) {
                int m = R0 + wm + tm * 16 + quad * 4 + r;
                float v = c[r];
                if (EPI == 0) {
                    v = silu_f(BNCF * (v + bias[n]));
                    v = silu_f(BNCF * (v * dww[n] + dwb[n]));
                } else if (EPI == 1) {
                    v = silu_f(BNCF * (v + bias[n]));
                    v = silu_f(BNCF * v);
                    v = silu_f(BNCF * (v * dww[n] + dwb[n]));
                } else if (EPI == 2) {
                    v = silu_f(BNCF * (v + bias[n]));
                    v = BNCF * v;
                } else {
                    v = BNCF * (v + bias[n]);
                    v = silu_f(v + res[(long)m * 128 + n]);
                }
                if (OD == 0)
                    ((u16*)Ov)[(long)m * Nn + n] = f2b(v);
                else
                    ((float*)Ov)[(long)m * Nn + n] = v;
            }
        }
    }
}

// ---------------------------------------------------------------- launcher
extern "C" void kernel_launch(void* const* d_in, const int* in_sizes, int n_in,
                              void* d_out, int out_size, void* d_ws, size_t ws_size,
                              hipStream_t stream) {
    const float* pos   = (const float*)d_in[0];
    const float* refl  = (const float*)d_in[1];
    const float* sfv   = (const float*)d_in[2];
    const int*   batch = (const int*)d_in[3];
    const int*   idxp  = (const int*)d_in[4];
    const int*   colp  = (const int*)d_in[5];
    const float* s_g  = (const float*)d_in[7];
    const float* s_b  = (const float*)d_in[8];
    const float* s_w1 = (const float*)d_in[9];
    const float* s_b1 = (const float*)d_in[10];
    const float* s_w2 = (const float*)d_in[11];
    const float* s_b2 = (const float*)d_in[12];
    const float* lkw  = (const float*)d_in[13];
    const float* lkb  = (const float*)d_in[14];
    const float* lng  = (const float*)d_in[15];
    const float* lnb  = (const float*)d_in[16];
    const float* l_w1 = (const float*)d_in[17];
    const float* l_b1 = (const float*)d_in[18];
    const float* l_w2 = (const float*)d_in[19];
    const float* l_b2 = (const float*)d_in[20];
    const float* expw = (const float*)d_in[21];
    const float* expb = (const float*)d_in[22];
    const float* dw1w = (const float*)d_in[23];
    const float* dw1b = (const float*)d_in[24];
    const float* pw1w = (const float*)d_in[25];
    const float* pw1b = (const float*)d_in[26];
    const float* dw2w = (const float*)d_in[27];
    const float* dw2b = (const float*)d_in[28];
    const float* pw2w = (const float*)d_in[29];
    const float* pw2b = (const float*)d_in[30];
    const float* prjw = (const float*)d_in[31];
    const float* prjb = (const float*)d_in[32];

    char* ws = (char*)d_ws;
    float* cent  = (float*)(ws + 0);                  // 64 B
    float* sfeat = (float*)(ws + 64);                 // M*3*4
    float* agg   = (float*)(ws + 393280);             // M*128*4 f32
    u16*   aggb  = (u16*)(ws + 17170496);             // M*128*2 bf16
    u16*   u1    = (u16*)(ws + 25559104);             // M*512*2
    u16*   u2    = (u16*)(ws + 59113536);             // M*512*2
    u16*   xf    = (u16*)(ws + 59113536);             // N*32*2 (aliases u2; dead before u2 written)
    u16*   expwt = (u16*)(ws + 92667968);             // 512*128*2
    u16*   pw1t  = (u16*)(ws + 92799040);             // 512*512*2
    u16*   pw2t  = (u16*)(ws + 93323328);             // 512*512*2
    u16*   prjt  = (u16*)(ws + 93847616);             // 128*512*2
    u16*   lw1t  = (u16*)(ws + 93978688);             // 64*64*2   = 8192
    u16*   lw2t  = (u16*)(ws + 93986880);             // 128*64*2  = 16384
    u16*   sw1t  = (u16*)(ws + 94003264);             // 64*128*2  = 16384
    u16*   sw2t  = (u16*)(ws + 94019648);             // 32*64*2   = 4096

    k_prep<<<2648, 256, 0, stream>>>(expw, expwt, pw1w, pw1t, pw2w, pw2t,
                                     prjw, prjt, l_w1, lw1t, l_w2, lw2t,
                                     s_w1, sw1t, s_w2, sw2t);

    hipMemsetAsync(cent, 0, 64, stream);
    k_centers<<<512, 256, 0, stream>>>(pos, sfv, batch, cent);
    k_stem<<<1024, 256, 0, stream>>>(pos, refl, sfv, batch, cent, s_g, s_b,
                                     sw1t, s_b1, sw2t, s_b2, xf);
    k_sfeat<<<128, 256, 0, stream>>>(pos, idxp, colp, lkw, lkb, lng, lnb, sfeat);
    k_edge<<<4096, 256, 0, stream>>>(pos, refl, idxp, colp, xf, sfeat,
                                     lw1t, l_b1, lw2t, l_b2, agg, aggb);

    dim3 blk(256);
    k_mgemm<0, 0><<<dim3(4, 256), blk, 0, stream>>>(aggb, expwt, expb, dw1w, dw1b,
                                                    nullptr, u1, 128, 512);
    k_mgemm<1, 0><<<dim3(4, 256), blk, 0, stream>>>(u1, pw1t, pw1b, dw2w, dw2b,
                                                    nullptr, u2, 512, 512);
    k_mgemm<2, 0><<<dim3(4, 256), blk, 0, stream>>>(u2, pw2t, pw2b, nullptr, nullptr,
                                                    nullptr, u1, 512, 512);
    k_mgemm<3, 1><<<dim3(1, 256), blk, 0, stream>>>(u1, prjt, prjb, nullptr, nullptr,
                                                    agg, d_out, 512, 128);
}